// Round 3
// baseline (605.961 us; speedup 1.0000x reference)
//
#include <hip/hip_runtime.h>

#define ANG 9
#define BATCH 4
#define CIN 64
#define COUT 64
#define HW 48
#define IN_HW 432
#define KK 81            // 9x9 taps
#define SPOS 2304        // 48*48
#define DDIM 68          // 17 disparities * 4 replicas

typedef __attribute__((ext_vector_type(8))) short short8;
typedef __attribute__((ext_vector_type(4))) float f32x4;

#define BSLAB (KK * SPOS * CIN)           // elems per batch in xvu = 11,943,936
#define XVU_ELEMS (4 * BSLAB)
#define XVU_BYTES (XVU_ELEMS * 2)         // 95,551,488
#define GUARD_BYTES 262144
#define WT_OFF_BYTES (XVU_BYTES + GUARD_BYTES)
#define WT_BYTES (COUT * KK * CIN * 2)    // 663,552
#define WS_NEEDED ((size_t)WT_OFF_BYTES + WT_BYTES)

__device__ __forceinline__ unsigned short f2bf(float f) {
  unsigned u = __float_as_uint(f);
  u += 0x7fffu + ((u >> 16) & 1u);        // round-to-nearest-even
  return (unsigned short)(u >> 16);
}

// ---------------------------------------------------------------------------
// convert_kernel: x[b][ci][iy][ix] fp32 -> xvu[b][uv][sy*48+sx][ci] bf16.
// iy = 9*sy + u, ix = 9*sx + v. One block per (b, u, sy).
// ---------------------------------------------------------------------------
__global__ __launch_bounds__(256) void convert_kernel(
    const float* __restrict__ x, unsigned short* __restrict__ xvu) {
  __shared__ unsigned short lsm[ANG * HW * CIN];  // [v][sx][ci] = 27648
  int q  = blockIdx.x;
  int sy = q % HW;
  int u  = (q / HW) % ANG;
  int b  = q / (HW * ANG);
  int iy = sy * ANG + u;

  int t  = threadIdx.x;
  int ci = t >> 2;
  int qq = t & 3;
  const float* xr = x + ((size_t)(b * CIN + ci) * IN_HW + iy) * IN_HW + qq * 108;
  int v = 0, sx = qq * 12;
#pragma unroll
  for (int g = 0; g < 27; ++g) {
    float4 f = *(const float4*)(xr + g * 4);
    lsm[(v * HW + sx) * CIN + ci] = f2bf(f.x); v++; if (v == 9) { v = 0; sx++; }
    lsm[(v * HW + sx) * CIN + ci] = f2bf(f.y); v++; if (v == 9) { v = 0; sx++; }
    lsm[(v * HW + sx) * CIN + ci] = f2bf(f.z); v++; if (v == 9) { v = 0; sx++; }
    lsm[(v * HW + sx) * CIN + ci] = f2bf(f.w); v++; if (v == 9) { v = 0; sx++; }
  }
  __syncthreads();
  const uint4* ls4 = (const uint4*)lsm;             // 3456 uint4
  uint4* dst = (uint4*)xvu;
  for (int s = t; s < 3456; s += 256) {
    int v2 = s / 384;                               // 384 uint4 per v
    int r  = s - v2 * 384;
    size_t o4 = (size_t)(b * KK + u * ANG + v2) * (SPOS * CIN / 8)
              + (size_t)sy * (HW * CIN / 8) + r;
    dst[o4] = ls4[s];
  }
}

// ---------------------------------------------------------------------------
// wprep_kernel: wt[co][uv][ci] = bf16(w[co][ci][uv])
// ---------------------------------------------------------------------------
__global__ __launch_bounds__(256) void wprep_kernel(
    const float* __restrict__ w, unsigned short* __restrict__ wt) {
  int s = blockIdx.x * 256 + threadIdx.x;   // < 64*81*64 = 331776
  int ci = s & 63;
  int tt = s >> 6;
  int uv = tt % KK;
  int co = tt / KK;
  wt[s] = f2bf(w[((size_t)co * CIN + ci) * KK + uv]);
}

// ---------------------------------------------------------------------------
// conv_mfma_kernel: K-split x3 implicit GEMM via light-field shear.
// Per (d,b,kc): partial D[co][sp] = sum_{uv in chunk kc} over 64 ci.
// Wave tile: M=64 co x N=48 spatial. Block = 4 waves = 192 spatial.
// Partial kc written to d_out slice 8*di + kc (even-t, rebuilt by expand).
// ---------------------------------------------------------------------------
__global__ __launch_bounds__(256, 2) void conv_mfma_kernel(
    const unsigned short* __restrict__ xvu,
    const unsigned short* __restrict__ wt,
    float* __restrict__ out) {
  int q    = blockIdx.x;
  int kc   = q % 3;                // K-chunk: uv in [27*kc, 27*kc+27)
  int mt12 = (q / 3) % 12;
  int b    = (q / 36) & 3;
  int di   = q / 144;              // 0..8 -> d = di-4
  int d    = di - 4;

  int tid  = threadIdx.x;
  int wid  = tid >> 6;
  int lane = tid & 63;
  int n16  = lane & 15;
  int kq   = lane >> 4;
  int n0   = mt12 * 192 + wid * 48;

  const unsigned short* xb = xvu + (size_t)b * BSLAB;
  int zoff = (4 - b) * BSLAB;      // zeroed guard, elem offset from xb

  int msp[3], oyv[3], oxv[3], xoffn[3];
#pragma unroll
  for (int nt = 0; nt < 3; ++nt) {
    msp[nt]   = n0 + nt * 16 + n16;
    oyv[nt]   = msp[nt] / 48;
    oxv[nt]   = msp[nt] - oyv[nt] * 48;
    xoffn[nt] = msp[nt] * 64 + kq * 8;
  }
  int vw[4];
#pragma unroll
  for (int mt = 0; mt < 4; ++mt) {
    int co = mt * 16 + n16;
    vw[mt] = co * (KK * CIN) + kq * 8;
  }

  f32x4 acc[4][3];
#pragma unroll
  for (int mt = 0; mt < 4; ++mt)
#pragma unroll
    for (int nt = 0; nt < 3; ++nt) acc[mt][nt] = (f32x4){0.f, 0.f, 0.f, 0.f};

  short8 wf0[4][2], xf0[3][2], wf1[4][2], xf1[3][2];

  auto LOAD = [&](int uv, short8 (&wf)[4][2], short8 (&xf)[3][2]) {
    int u   = (uv * 57) >> 9;                 // uv/9 for uv<=80
    int v   = uv - u * 9;
    int uvs = (d > 0) ? (80 - uv) : uv;       // kernel flip for d>0
    const unsigned short* wp = wt + uvs * CIN;
#pragma unroll
    for (int mt = 0; mt < 4; ++mt) {
      wf[mt][0] = *(const short8*)(wp + vw[mt]);
      wf[mt][1] = *(const short8*)(wp + vw[mt] + 32);
    }
    int dy = d * (u - 4), dx = d * (v - 4);
    int soff = (uv * SPOS - (dy * 48 + dx)) * 64;
#pragma unroll
    for (int nt = 0; nt < 3; ++nt) {
      bool ok = ((unsigned)(oyv[nt] - dy) < 48u) && ((unsigned)(oxv[nt] - dx) < 48u);
      int off = ok ? (xoffn[nt] + soff) : zoff;
      xf[nt][0] = *(const short8*)(xb + off);
      xf[nt][1] = *(const short8*)(xb + off + 32);
    }
  };
  auto MF = [&](short8 (&wf)[4][2], short8 (&xf)[3][2]) {
#pragma unroll
    for (int mt = 0; mt < 4; ++mt)
#pragma unroll
      for (int nt = 0; nt < 3; ++nt) {
        acc[mt][nt] = __builtin_amdgcn_mfma_f32_16x16x32_bf16(
            wf[mt][0], xf[nt][0], acc[mt][nt], 0, 0, 0);
        acc[mt][nt] = __builtin_amdgcn_mfma_f32_16x16x32_bf16(
            wf[mt][1], xf[nt][1], acc[mt][nt], 0, 0, 0);
      }
  };

  int s0 = kc * 27;
  LOAD(s0, wf0, xf0);
#pragma unroll 1
  for (int j = 0; j < 26; j += 2) {
    LOAD(s0 + j + 1, wf1, xf1);
    MF(wf0, xf0);
    LOAD(s0 + j + 2, wf0, xf0);   // max arg = s0+26 <= 80
    MF(wf1, xf1);
  }
  MF(wf0, xf0);                   // uv = s0+26

  // Epilogue: C/D layout col=lane&15 (spatial), row=kq*4+reg (co within tile)
#pragma unroll
  for (int mt = 0; mt < 4; ++mt) {
#pragma unroll
    for (int r = 0; r < 4; ++r) {
      int co = mt * 16 + kq * 4 + r;
      size_t ob = ((size_t)(b * COUT + co) * DDIM + 8 * di + kc) * SPOS;
#pragma unroll
      for (int nt = 0; nt < 3; ++nt) out[ob + msp[nt]] = acc[mt][nt][r];
    }
  }
}

// ---------------------------------------------------------------------------
// expand_kernel: single streaming pass. Reads the nparts partial slices per
// integer disparity (stashed at t = 8*jj + r), sums them, then writes all 68
// output slices: even-t groups = 0, odd-t groups = 0.5*(tv[jj]+tv[jj+1]) x4.
// Each thread owns one (b,co,s) column -> read-before-overwrite is safe.
// ---------------------------------------------------------------------------
__global__ __launch_bounds__(256) void expand_kernel(float* __restrict__ out,
                                                     int nparts) {
  int p  = blockIdx.x * 256 + threadIdx.x;   // < 4*64*2304
  int bc = p / SPOS;
  int s  = p - bc * SPOS;
  size_t base = (size_t)bc * DDIM * SPOS + s;
  float tv[9];
#pragma unroll
  for (int jj = 0; jj < 9; ++jj) {
    float v = out[base + (size_t)(8 * jj) * SPOS];
    if (nparts == 3)
      v += out[base + (size_t)(8 * jj + 1) * SPOS]
         + out[base + (size_t)(8 * jj + 2) * SPOS];
    tv[jj] = v;
  }
#pragma unroll
  for (int jj = 0; jj < 9; ++jj) {
    size_t o = base + (size_t)(8 * jj) * SPOS;
    out[o] = 0.f; out[o + SPOS] = 0.f; out[o + 2 * SPOS] = 0.f; out[o + 3 * SPOS] = 0.f;
  }
#pragma unroll
  for (int jj = 0; jj < 8; ++jj) {
    float v = 0.5f * (tv[jj] + tv[jj + 1]);
    size_t o = base + (size_t)(8 * jj + 4) * SPOS;
    out[o] = v; out[o + SPOS] = v; out[o + 2 * SPOS] = v; out[o + 3 * SPOS] = v;
  }
}

// ---------------------------------------------------------------------------
// R1 fallback conv (fp32, used only if ws_size is too small)
// ---------------------------------------------------------------------------
__global__ __launch_bounds__(256, 4) void conv_kernel(
    const float* __restrict__ x, const float* __restrict__ w,
    float* __restrict__ out) {
  __shared__ float lw[COUT * KK];
  __shared__ float lx[KK * 32];
  int bi  = blockIdx.x;
  int oxt = bi % 3;
  int oy2 = (bi / 3) % 24;
  int b   = (bi / 72) % BATCH;
  int di  = bi / 288;
  int d   = di - 4;
  int dil, pad;
  if (d < 0)       { dil = (-d) * ANG + 1; pad = (-d) * 36; }
  else if (d == 0) { dil = 1;              pad = 0; }
  else             { dil = d * ANG - 1;    pad = d * 36 - 8; }
  int t = threadIdx.x, tx = t & 15, ty = t >> 4;
  float acc[4][2] = {};
  const float* xb = x + (size_t)b * CIN * IN_HW * IN_HW;
  for (int ci = 0; ci < CIN; ++ci) {
    __syncthreads();
    for (int s = t; s < COUT * KK; s += 256) {
      int co = s / KK, k = s - co * KK;
      lw[s] = w[((size_t)co * CIN + ci) * KK + k];
    }
    const float* xc = xb + (size_t)ci * IN_HW * IN_HW;
    for (int s = t; s < KK * 32; s += 256) {
      int k = s >> 5, rem = s & 31, r = rem >> 4, c = rem & 15;
      int ky = k / ANG, kx = k - ky * ANG;
      int iy = (oy2 * 2 + r) * ANG - pad + ky * dil;
      int ix = (oxt * 16 + c) * ANG - pad + kx * dil;
      float vv = 0.f;
      if ((unsigned)iy < IN_HW && (unsigned)ix < IN_HW) vv = xc[iy * IN_HW + ix];
      lx[s] = vv;
    }
    __syncthreads();
    const float* lwp = lw + ty * 4 * KK;
#pragma unroll 9
    for (int k = 0; k < KK; ++k) {
      float x0 = lx[k * 32 + tx], x1 = lx[k * 32 + 16 + tx];
      float w0 = lwp[k], w1 = lwp[k + KK], w2 = lwp[k + 2 * KK], w3 = lwp[k + 3 * KK];
      acc[0][0] += w0 * x0; acc[0][1] += w0 * x1;
      acc[1][0] += w1 * x0; acc[1][1] += w1 * x1;
      acc[2][0] += w2 * x0; acc[2][1] += w2 * x1;
      acc[3][0] += w3 * x0; acc[3][1] += w3 * x1;
    }
  }
  int oy = oy2 * 2, ox = oxt * 16 + tx;
#pragma unroll
  for (int j = 0; j < 4; ++j) {
    int co = ty * 4 + j;
    size_t base = (((size_t)(b * COUT + co) * DDIM) + 8 * di) * SPOS;
    out[base + (size_t)oy * HW + ox]       = acc[j][0];
    out[base + (size_t)(oy + 1) * HW + ox] = acc[j][1];
  }
}

extern "C" void kernel_launch(void* const* d_in, const int* in_sizes, int n_in,
                              void* d_out, int out_size, void* d_ws, size_t ws_size,
                              hipStream_t stream) {
  const float* x = (const float*)d_in[0];   // [4, 64, 432, 432]
  const float* w = (const float*)d_in[1];   // [64, 64, 9, 9]
  float* out = (float*)d_out;               // [4, 64, 68, 48, 48]

  if (ws_size >= WS_NEEDED) {
    unsigned short* xvu = (unsigned short*)d_ws;
    unsigned short* wt  = (unsigned short*)((char*)d_ws + WT_OFF_BYTES);
    hipMemsetAsync((char*)d_ws + XVU_BYTES, 0, GUARD_BYTES, stream);
    wprep_kernel<<<dim3(1296), dim3(256), 0, stream>>>(w, wt);
    convert_kernel<<<dim3(BATCH * ANG * HW), dim3(256), 0, stream>>>(x, xvu);
    conv_mfma_kernel<<<dim3(9 * BATCH * 12 * 3), dim3(256), 0, stream>>>(xvu, wt, out);
    expand_kernel<<<dim3((BATCH * COUT * SPOS) / 256), dim3(256), 0, stream>>>(out, 3);
  } else {
    conv_kernel<<<dim3(9 * 4 * 24 * 3), dim3(256), 0, stream>>>(x, w, out);
    expand_kernel<<<dim3((BATCH * COUT * SPOS) / 256), dim3(256), 0, stream>>>(out, 1);
  }
}

// Round 4
// 493.717 us; speedup vs baseline: 1.2273x; 1.2273x over previous
//
#include <hip/hip_runtime.h>

#define ANG 9
#define BATCH 4
#define CIN 64
#define COUT 64
#define HW 48
#define IN_HW 432
#define KK 81            // 9x9 taps
#define SPOS 2304        // 48*48
#define DDIM 68          // 17 disparities * 4 replicas

typedef __attribute__((ext_vector_type(8))) short short8;
typedef __attribute__((ext_vector_type(4))) float f32x4;

// xvu (lives in d_out during build): [b][uv][sy 48][cig 8][sxp 80][cil 8] bf16
// sxp = sx + 16; sxp in [0,16) and [64,80) are zero margins (absorb dx shear).
#define XV_UVSTRIDE (48 * 8 * 80 * 8)   // 245760 elems per (b,uv)
#define XV_ROW (8 * 80 * 8)             // 5120 elems per sy row
#define XV_CIG (80 * 8)                 // 640 elems per cig
#define XV_TOTAL_B ((size_t)BATCH * KK * XV_UVSTRIDE * 2)  // 159,252,480 <= out bytes

// ws layout: [ppart 63.7MB][wt2 663KB][zrow 10KB]
#define PPART_ELEMS (27 * 4 * 64 * 2304)        // 15,925,248 floats
#define WT2_OFF_B ((size_t)PPART_ELEMS * 4)     // 63,700,992
#define WT2_ELEMS (KK * 8 * 64 * 8)             // 331,776
#define ZROW_OFF_B (WT2_OFF_B + (size_t)WT2_ELEMS * 2)
#define ZROW_ELEMS 5120
#define WS_NEEDED (ZROW_OFF_B + (size_t)ZROW_ELEMS * 2)   // ~64.4 MB

__device__ __forceinline__ unsigned short f2bf(float f) {
  unsigned u = __float_as_uint(f);
  u += 0x7fffu + ((u >> 16) & 1u);        // round-to-nearest-even
  return (unsigned short)(u >> 16);
}

// ---------------------------------------------------------------------------
// convert_kernel: x[b][ci][iy][ix] fp32 -> xvu[b][uv][sy][cig][sxp][cil] bf16
// (iy = 9*sy+u, ix = 9*sx+v). One block per (b,u,sy). Phase 1: coalesced
// float4 reads along ix (lanes consecutive in fx), scatter to XOR-swizzled
// LDS. Phase 2: read 16B ci-chunks from LDS, write coalesced uint4 runs
// including the zero margins.
// ---------------------------------------------------------------------------
__global__ __launch_bounds__(256) void convert_kernel(
    const float* __restrict__ x, unsigned short* __restrict__ xvu) {
  __shared__ unsigned short lsm[ANG * HW * CIN];  // [v][sx][ci-swizzled]
  int q  = blockIdx.x;
  int sy = q % HW;
  int u  = (q / HW) % ANG;
  int b  = q / (HW * ANG);
  int iy = sy * ANG + u;
  int t  = threadIdx.x;

  // Phase 1: 64 ci rows x 108 float4 = 6912 float4, lanes consecutive in fx.
  for (int it = 0; it < 27; ++it) {
    unsigned idx = it * 256 + t;
    unsigned ci  = idx / 108u;
    unsigned fx  = idx - ci * 108u;
    const float* p = x + (((size_t)(b * CIN + ci) * IN_HW) + iy) * IN_HW + fx * 4;
    float4 f = *(const float4*)p;
    int ix = fx * 4;
    float fv[4] = {f.x, f.y, f.z, f.w};
#pragma unroll
    for (int k2 = 0; k2 < 4; ++k2) {
      int v  = (ix + k2) % 9;
      int sx = (ix + k2) / 9;
      int cisw = ((((int)ci >> 3) ^ (sx & 7)) << 3) | ((int)ci & 7);
      lsm[(v * HW + sx) * CIN + cisw] = f2bf(fv[k2]);
    }
  }
  __syncthreads();

  // Phase 2: write [v][cig][sxp] uint4 (8 cil elems), margins = 0.
  uint4* dst = (uint4*)xvu;
  size_t base_u4 = (size_t)(b * KK + u * ANG) * (XV_UVSTRIDE / 8)
                 + (size_t)sy * (XV_ROW / 8);
  const uint4* ls4 = (const uint4*)lsm;
  for (int s = t; s < 9 * 8 * 80; s += 256) {   // 5760
    int v2  = s / 640;
    int rem = s - v2 * 640;
    int cig = rem / 80;
    int sxp = rem - cig * 80;
    uint4 val = {0u, 0u, 0u, 0u};
    if (sxp >= 16 && sxp < 64) {
      int sx   = sxp - 16;
      int cig2 = cig ^ (sx & 7);
      val = ls4[((v2 * HW + sx) * CIN + cig2 * 8) >> 3];
    }
    dst[base_u4 + (size_t)v2 * (XV_UVSTRIDE / 8) + cig * 80 + sxp] = val;
  }
}

// ---------------------------------------------------------------------------
// wprep_kernel: wt2[uv][cig][co][cil] = bf16(w[co][cig*8+cil][uv])
// ---------------------------------------------------------------------------
__global__ __launch_bounds__(256) void wprep_kernel(
    const float* __restrict__ w, unsigned short* __restrict__ wt2) {
  int s   = blockIdx.x * 256 + threadIdx.x;   // < 331776
  int cil = s & 7;
  int co  = (s >> 3) & 63;
  int cig = (s >> 9) & 7;
  int uv  = s >> 12;
  wt2[s] = f2bf(w[((size_t)co * CIN + cig * 8 + cil) * KK + uv]);
}

// ---------------------------------------------------------------------------
// conv_mfma_kernel: K-split x3 implicit GEMM, fragment-major layouts.
// Wave = one sy row (48 sp); dy validity is wave-uniform -> zrow select;
// dx shear absorbed by sxp margins. All fragment loads: 16 lanes x 16B
// contiguous (4 x 256B segments per instr).
// ---------------------------------------------------------------------------
__global__ __launch_bounds__(256, 2) void conv_mfma_kernel(
    const unsigned short* __restrict__ xvu,
    const unsigned short* __restrict__ wt2,
    const unsigned short* __restrict__ zrow,
    float* __restrict__ ppart) {
  int q    = blockIdx.x;
  int kc   = q % 3;
  int mt12 = (q / 3) % 12;
  int b    = (q / 36) & 3;
  int di   = q / 144;              // 0..8 -> d = di-4
  int d    = di - 4;

  int tid  = threadIdx.x;
  int wid  = tid >> 6;
  int lane = tid & 63;
  int n16  = lane & 15;
  int kq   = lane >> 4;
  int sy   = mt12 * 4 + wid;       // wave's output row

  int wlane = kq * 512 + n16 * 8;              // wt2 lane offset
  int xlane = kq * XV_CIG + (n16 + 16) * 8;    // xvu lane offset (pre-dx)

  f32x4 acc[4][3];
#pragma unroll
  for (int mt = 0; mt < 4; ++mt)
#pragma unroll
    for (int nt = 0; nt < 3; ++nt) acc[mt][nt] = (f32x4){0.f, 0.f, 0.f, 0.f};

  short8 wf0[4][2], xf0[3][2], wf1[4][2], xf1[3][2];

  auto LOAD = [&](int uv, short8 (&wf)[4][2], short8 (&xf)[3][2]) {
    int u   = (uv * 57) >> 9;                 // uv/9 for uv<=80
    int v   = uv - u * 9;
    int uvs = (d > 0) ? (80 - uv) : uv;       // kernel flip for d>0
    const unsigned short* wp = wt2 + uvs * 4096 + wlane;
#pragma unroll
    for (int mt = 0; mt < 4; ++mt) {
      wf[mt][0] = *(const short8*)(wp + mt * 128);
      wf[mt][1] = *(const short8*)(wp + mt * 128 + 2048);
    }
    int dy = d * (u - 4), dx = d * (v - 4);
    unsigned syi = (unsigned)(sy - dy);
    const unsigned short* xp = (syi < 48u)
        ? xvu + (size_t)(b * KK + uv) * XV_UVSTRIDE + (size_t)syi * XV_ROW
        : zrow;
    xp += xlane - dx * 8;
#pragma unroll
    for (int nt = 0; nt < 3; ++nt) {
      xf[nt][0] = *(const short8*)(xp + nt * 128);
      xf[nt][1] = *(const short8*)(xp + nt * 128 + 4 * XV_CIG);
    }
  };
  auto MF = [&](short8 (&wf)[4][2], short8 (&xf)[3][2]) {
#pragma unroll
    for (int mt = 0; mt < 4; ++mt)
#pragma unroll
      for (int nt = 0; nt < 3; ++nt) {
        acc[mt][nt] = __builtin_amdgcn_mfma_f32_16x16x32_bf16(
            wf[mt][0], xf[nt][0], acc[mt][nt], 0, 0, 0);
        acc[mt][nt] = __builtin_amdgcn_mfma_f32_16x16x32_bf16(
            wf[mt][1], xf[nt][1], acc[mt][nt], 0, 0, 0);
      }
  };

  int s0 = kc * 27;
  LOAD(s0, wf0, xf0);
#pragma unroll 1
  for (int j = 0; j < 26; j += 2) {
    LOAD(s0 + j + 1, wf1, xf1);
    MF(wf0, xf0);
    LOAD(s0 + j + 2, wf0, xf0);   // max arg = s0+26 <= 80
    MF(wf1, xf1);
  }
  MF(wf0, xf0);                   // uv = s0+26

  // Epilogue: C/D col = n16 -> sp within row; row = kq*4+reg -> co in tile.
  float* pb = ppart + ((size_t)((di * 3 + kc) * 4 + b)) * COUT * SPOS + sy * 48;
#pragma unroll
  for (int mt = 0; mt < 4; ++mt) {
#pragma unroll
    for (int r = 0; r < 4; ++r) {
      int co = mt * 16 + kq * 4 + r;
      float* o = pb + (size_t)co * SPOS;
#pragma unroll
      for (int nt = 0; nt < 3; ++nt) o[nt * 16 + n16] = acc[mt][nt][r];
    }
  }
}

// ---------------------------------------------------------------------------
// expand_kernel: reads 27 partials from ws, sums triples, writes all 68
// output slices (even-t groups = 0, odd-t = 0.5*(tv[j]+tv[j+1]) x4).
// ---------------------------------------------------------------------------
__global__ __launch_bounds__(256) void expand_kernel(
    const float* __restrict__ ppart, float* __restrict__ out) {
  int p  = blockIdx.x * 256 + threadIdx.x;   // < 4*64*2304 = 589824
  int bc = p / SPOS;
  int s  = p - bc * SPOS;
  float tv[9];
#pragma unroll
  for (int jj = 0; jj < 9; ++jj) {
    tv[jj] = ppart[(size_t)(jj * 3 + 0) * 589824 + p]
           + ppart[(size_t)(jj * 3 + 1) * 589824 + p]
           + ppart[(size_t)(jj * 3 + 2) * 589824 + p];
  }
  size_t base = (size_t)bc * DDIM * SPOS + s;
#pragma unroll
  for (int jj = 0; jj < 9; ++jj) {
    size_t o = base + (size_t)(8 * jj) * SPOS;
    out[o] = 0.f; out[o + SPOS] = 0.f; out[o + 2 * SPOS] = 0.f; out[o + 3 * SPOS] = 0.f;
  }
#pragma unroll
  for (int jj = 0; jj < 8; ++jj) {
    float v = 0.5f * (tv[jj] + tv[jj + 1]);
    size_t o = base + (size_t)(8 * jj + 4) * SPOS;
    out[o] = v; out[o + SPOS] = v; out[o + 2 * SPOS] = v; out[o + 3 * SPOS] = v;
  }
}

// ---------------------------------------------------------------------------
// Fallback path (tiny ws): R1 fp32 conv stashing into d_out even slices +
// in-place expand.
// ---------------------------------------------------------------------------
__global__ __launch_bounds__(256, 4) void conv_kernel(
    const float* __restrict__ x, const float* __restrict__ w,
    float* __restrict__ out) {
  __shared__ float lw[COUT * KK];
  __shared__ float lx[KK * 32];
  int bi  = blockIdx.x;
  int oxt = bi % 3;
  int oy2 = (bi / 3) % 24;
  int b   = (bi / 72) % BATCH;
  int di  = bi / 288;
  int d   = di - 4;
  int dil, pad;
  if (d < 0)       { dil = (-d) * ANG + 1; pad = (-d) * 36; }
  else if (d == 0) { dil = 1;              pad = 0; }
  else             { dil = d * ANG - 1;    pad = d * 36 - 8; }
  int t = threadIdx.x, tx = t & 15, ty = t >> 4;
  float acc[4][2] = {};
  const float* xb = x + (size_t)b * CIN * IN_HW * IN_HW;
  for (int ci = 0; ci < CIN; ++ci) {
    __syncthreads();
    for (int s = t; s < COUT * KK; s += 256) {
      int co = s / KK, k = s - co * KK;
      lw[s] = w[((size_t)co * CIN + ci) * KK + k];
    }
    const float* xc = xb + (size_t)ci * IN_HW * IN_HW;
    for (int s = t; s < KK * 32; s += 256) {
      int k = s >> 5, rem = s & 31, r = rem >> 4, c = rem & 15;
      int ky = k / ANG, kx = k - ky * ANG;
      int iy = (oy2 * 2 + r) * ANG - pad + ky * dil;
      int ix = (oxt * 16 + c) * ANG - pad + kx * dil;
      float vv = 0.f;
      if ((unsigned)iy < IN_HW && (unsigned)ix < IN_HW) vv = xc[iy * IN_HW + ix];
      lx[s] = vv;
    }
    __syncthreads();
    const float* lwp = lw + ty * 4 * KK;
#pragma unroll 9
    for (int k = 0; k < KK; ++k) {
      float x0 = lx[k * 32 + tx], x1 = lx[k * 32 + 16 + tx];
      float w0 = lwp[k], w1 = lwp[k + KK], w2 = lwp[k + 2 * KK], w3 = lwp[k + 3 * KK];
      acc[0][0] += w0 * x0; acc[0][1] += w0 * x1;
      acc[1][0] += w1 * x0; acc[1][1] += w1 * x1;
      acc[2][0] += w2 * x0; acc[2][1] += w2 * x1;
      acc[3][0] += w3 * x0; acc[3][1] += w3 * x1;
    }
  }
  int oy = oy2 * 2, ox = oxt * 16 + tx;
#pragma unroll
  for (int j = 0; j < 4; ++j) {
    int co = ty * 4 + j;
    size_t base = (((size_t)(b * COUT + co) * DDIM) + 8 * di) * SPOS;
    out[base + (size_t)oy * HW + ox]       = acc[j][0];
    out[base + (size_t)(oy + 1) * HW + ox] = acc[j][1];
  }
}

__global__ __launch_bounds__(256) void expand_inplace_kernel(float* __restrict__ out) {
  int p  = blockIdx.x * 256 + threadIdx.x;
  int bc = p / SPOS;
  int s  = p - bc * SPOS;
  size_t base = (size_t)bc * DDIM * SPOS + s;
  float tv[9];
#pragma unroll
  for (int jj = 0; jj < 9; ++jj) tv[jj] = out[base + (size_t)(8 * jj) * SPOS];
#pragma unroll
  for (int jj = 0; jj < 9; ++jj) {
    size_t o = base + (size_t)(8 * jj) * SPOS;
    out[o] = 0.f; out[o + SPOS] = 0.f; out[o + 2 * SPOS] = 0.f; out[o + 3 * SPOS] = 0.f;
  }
#pragma unroll
  for (int jj = 0; jj < 8; ++jj) {
    float v = 0.5f * (tv[jj] + tv[jj + 1]);
    size_t o = base + (size_t)(8 * jj + 4) * SPOS;
    out[o] = v; out[o + SPOS] = v; out[o + 2 * SPOS] = v; out[o + 3 * SPOS] = v;
  }
}

extern "C" void kernel_launch(void* const* d_in, const int* in_sizes, int n_in,
                              void* d_out, int out_size, void* d_ws, size_t ws_size,
                              hipStream_t stream) {
  const float* x = (const float*)d_in[0];   // [4, 64, 432, 432]
  const float* w = (const float*)d_in[1];   // [64, 64, 9, 9]
  float* out = (float*)d_out;               // [4, 64, 68, 48, 48]

  if (ws_size >= WS_NEEDED) {
    float* ppart = (float*)d_ws;
    unsigned short* wt2  = (unsigned short*)((char*)d_ws + WT2_OFF_B);
    unsigned short* zrow = (unsigned short*)((char*)d_ws + ZROW_OFF_B);
    unsigned short* xvu  = (unsigned short*)d_out;   // build area inside d_out

    hipMemsetAsync(zrow, 0, ZROW_ELEMS * 2, stream);
    wprep_kernel<<<dim3(WT2_ELEMS / 256), dim3(256), 0, stream>>>(w, wt2);
    convert_kernel<<<dim3(BATCH * ANG * HW), dim3(256), 0, stream>>>(x, xvu);
    conv_mfma_kernel<<<dim3(9 * 4 * 12 * 3), dim3(256), 0, stream>>>(xvu, wt2, zrow, ppart);
    expand_kernel<<<dim3((BATCH * COUT * SPOS) / 256), dim3(256), 0, stream>>>(ppart, out);
  } else {
    conv_kernel<<<dim3(9 * 4 * 24 * 3), dim3(256), 0, stream>>>(x, w, out);
    expand_inplace_kernel<<<dim3((BATCH * COUT * SPOS) / 256), dim3(256), 0, stream>>>(out);
  }
}